// Round 1
// 19254.366 us; speedup vs baseline: 1.5242x; 1.5242x over previous
//
#include <hip/hip_runtime.h>
#include <cmath>

#define TOK 4608      // B*N
#define DMODEL 768

__device__ __forceinline__ float gelu_exact(float x) {
    return 0.5f * x * (1.0f + erff(x * 0.70710678118654752440f));
}

// ---------------- patch embed: tok[b*576+n][d] ----------------
__global__ __launch_bounds__(256)
void patch_embed_kernel(const float* __restrict__ x, const float* __restrict__ pw,
                        const float* __restrict__ pb, const float* __restrict__ pos,
                        float* __restrict__ tok)
{
    int tokid = blockIdx.x;          // b*576 + n
    int b = tokid / 576, n = tokid % 576;
    int hp = n / 24, wp = n % 24;
    int t = threadIdx.x;
    __shared__ float patch[256];
    int ph = t >> 4, pwx = t & 15;
    patch[t] = x[(size_t)b*147456 + (size_t)(hp*16+ph)*384 + (wp*16+pwx)];
    __syncthreads();
    #pragma unroll
    for (int rep = 0; rep < 3; ++rep) {
        int d = t + rep*256;
        const float* wrow = pw + (size_t)d*256;
        float s = 0.f;
        for (int k = 0; k < 256; k += 4) {
            s = fmaf(patch[k],   wrow[k],   s);
            s = fmaf(patch[k+1], wrow[k+1], s);
            s = fmaf(patch[k+2], wrow[k+2], s);
            s = fmaf(patch[k+3], wrow[k+3], s);
        }
        tok[(size_t)tokid*768 + d] = s + pb[d] + pos[(size_t)n*768 + d];
    }
}

// ---------------- LayerNorm over D=768, one block per token ----------------
__global__ __launch_bounds__(256)
void ln_kernel(const float* __restrict__ in, float* __restrict__ out,
               const float* __restrict__ g, const float* __restrict__ bta)
{
    int tokid = blockIdx.x;
    const float* xr = in + (size_t)tokid*768;
    int t = threadIdx.x;
    float v0 = xr[t], v1 = xr[t+256], v2 = xr[t+512];
    float s = v0+v1+v2, q = v0*v0+v1*v1+v2*v2;
    for (int off = 32; off > 0; off >>= 1) {
        s += __shfl_down(s, off);
        q += __shfl_down(q, off);
    }
    __shared__ float ss[4], sq[4];
    int wv = t >> 6, ln = t & 63;
    if (ln == 0) { ss[wv] = s; sq[wv] = q; }
    __syncthreads();
    float ts = ss[0]+ss[1]+ss[2]+ss[3];
    float tq = sq[0]+sq[1]+sq[2]+sq[3];
    float mean = ts * (1.f/768.f);
    float var  = tq * (1.f/768.f) - mean*mean;
    float inv  = rsqrtf(var + 1e-5f);
    float* orow = out + (size_t)tokid*768;
    orow[t]     = (v0-mean)*inv*g[t]     + bta[t];
    orow[t+256] = (v1-mean)*inv*g[t+256] + bta[t+256];
    orow[t+512] = (v2-mean)*inv*g[t+512] + bta[t+512];
}

// ---------------- tiled NT GEMM: C[m,n] = sum_k A[row(m),k]*Bw[n,k] (+bias) --------
// mode 0: C = val       mode 1: C += val (residual)
// mode 2: C[gather] = gelu(val)   mode 3: C[gather] += wgt*val
// LDS rows padded 64->68: staging-write conflicts 4-way -> 2-way (free).
__global__ __launch_bounds__(256)
void gemm_nt(const float* __restrict__ A, const float* __restrict__ Bw,
             const float* __restrict__ bias, float* __restrict__ C,
             int M, int Nout, int K, int ldA, int ldC, int mode,
             const int* __restrict__ lists, const int* __restrict__ counts,
             const float* __restrict__ wgt)
{
    int Meff = M;
    const int* gather = nullptr;
    if (counts) {
        int e = blockIdx.z;
        Meff   = counts[e];
        gather = lists + e * TOK;
        Bw    += (size_t)e * Nout * K;
        bias  += (size_t)e * Nout;
    }
    int m0 = blockIdx.y << 6, n0 = blockIdx.x << 6;
    if (m0 >= Meff) return;

    __shared__ float As[16][68];
    __shared__ float Bs[16][68];
    int t  = threadIdx.x;
    int lm = t >> 2, lk = (t & 3) << 2;   // staging: row-in-tile, k-in-tile
    int tx = t & 15, ty = t >> 4;         // compute: 4x4 per thread

    int ar = m0 + lm;
    long agrow = -1;
    if (ar < Meff) agrow = gather ? gather[ar] : ar;
    const float* Arow = (agrow >= 0) ? (A + (size_t)agrow*ldA + lk) : A;
    const float* Brow = Bw + (size_t)(n0 + lm)*K + lk;

    float acc[4][4] = {};
    for (int k0 = 0; k0 < K; k0 += 16) {
        float4 av = make_float4(0.f,0.f,0.f,0.f);
        if (agrow >= 0) av = *(const float4*)(Arow + k0);
        float4 bv = *(const float4*)(Brow + k0);
        As[lk+0][lm]=av.x; As[lk+1][lm]=av.y; As[lk+2][lm]=av.z; As[lk+3][lm]=av.w;
        Bs[lk+0][lm]=bv.x; Bs[lk+1][lm]=bv.y; Bs[lk+2][lm]=bv.z; Bs[lk+3][lm]=bv.w;
        __syncthreads();
        #pragma unroll
        for (int kk = 0; kk < 16; ++kk) {
            float af[4], bf[4];
            *(float4*)af = *(const float4*)&As[kk][ty<<2];
            *(float4*)bf = *(const float4*)&Bs[kk][tx<<2];
            #pragma unroll
            for (int i = 0; i < 4; ++i)
                #pragma unroll
                for (int j = 0; j < 4; ++j)
                    acc[i][j] = fmaf(af[i], bf[j], acc[i][j]);
        }
        __syncthreads();
    }

    #pragma unroll
    for (int i = 0; i < 4; ++i) {
        int m = m0 + (ty<<2) + i;
        if (m >= Meff) continue;
        int row = gather ? gather[m] : m;
        #pragma unroll
        for (int j = 0; j < 4; ++j) {
            int n = n0 + (tx<<2) + j;
            float val = acc[i][j] + bias[n];
            size_t oidx = (size_t)row*ldC + n;
            if      (mode == 0) C[oidx] = val;
            else if (mode == 1) C[oidx] += val;
            else if (mode == 2) C[oidx] = gelu_exact(val);
            else                C[oidx] += wgt[row] * val;
        }
    }
}

// ---------------- attention: one block = (16 q-rows, head, batch) ----------------
// LDS padding: qs/kt stride 64->68 (kills the 16-way kt conflict -> 2-way),
// sc stride 576->592 (stride%32==16 -> 2-way everywhere).
// PV stages V tiles through LDS (reusing kt): V read once per block instead of
// 4x from global, sc consumed as wave-uniform float4 broadcasts.
__global__ __launch_bounds__(256)
void attn_kernel(const float* __restrict__ qkv, float* __restrict__ attn)
{
    int q0 = blockIdx.x << 4;
    int h  = blockIdx.y;
    int b  = blockIdx.z;
    const float* base = qkv + (size_t)b * 576 * 2304;
    int qoff = h << 6, koff = 768 + (h<<6), voff = 1536 + (h<<6);
    __shared__ float qs[16][68], kt[16][68];
    __shared__ float sc[16][592];
    __shared__ float ssum[16];
    int t = threadIdx.x;
    int r = t >> 4, c4 = (t & 15) << 2;
    *(float4*)&qs[r][c4] = *(const float4*)&base[(size_t)(q0 + r)*2304 + qoff + c4];
    __syncthreads();
    int jj = t & 15;
    for (int j0 = 0; j0 < 576; j0 += 16) {
        *(float4*)&kt[r][c4] = *(const float4*)&base[(size_t)(j0 + r)*2304 + koff + c4];
        __syncthreads();
        float s = 0.f;
        #pragma unroll
        for (int d = 0; d < 64; d += 4) {
            float qa[4], ka[4];
            *(float4*)qa = *(const float4*)&qs[r][d];
            *(float4*)ka = *(const float4*)&kt[jj][d];
            s = fmaf(qa[0],ka[0], fmaf(qa[1],ka[1], fmaf(qa[2],ka[2], fmaf(qa[3],ka[3], s))));
        }
        sc[r][j0 + jj] = s * 0.125f;
        __syncthreads();
    }
    // softmax per row: 16 threads per row (same wave), keep un-normalized exp + sum
    {
        int row = t >> 4, l16 = t & 15;
        float mx = -3.4e38f;
        for (int j = l16; j < 576; j += 16) mx = fmaxf(mx, sc[row][j]);
        #pragma unroll
        for (int off = 8; off > 0; off >>= 1) mx = fmaxf(mx, __shfl_xor(mx, off, 16));
        float sum = 0.f;
        for (int j = l16; j < 576; j += 16) {
            float e = expf(sc[row][j] - mx);
            sc[row][j] = e;
            sum += e;
        }
        #pragma unroll
        for (int off = 8; off > 0; off >>= 1) sum += __shfl_xor(sum, off, 16);
        if (l16 == 0) ssum[row] = sum;
    }
    __syncthreads();
    // PV: thread handles (d = t&63, rows rb..rb+3); V staged through LDS (kt reused)
    int d = t & 63, rb = (t >> 6) << 2;
    float acc[4] = {0.f,0.f,0.f,0.f};
    for (int j0 = 0; j0 < 576; j0 += 16) {
        *(float4*)&kt[r][c4] = *(const float4*)&base[(size_t)(j0 + r)*2304 + voff + c4];
        __syncthreads();
        #pragma unroll
        for (int jj4 = 0; jj4 < 16; jj4 += 4) {
            float a0[4], a1[4], a2[4], a3[4];
            *(float4*)a0 = *(const float4*)&sc[rb+0][j0+jj4];
            *(float4*)a1 = *(const float4*)&sc[rb+1][j0+jj4];
            *(float4*)a2 = *(const float4*)&sc[rb+2][j0+jj4];
            *(float4*)a3 = *(const float4*)&sc[rb+3][j0+jj4];
            #pragma unroll
            for (int u = 0; u < 4; ++u) {
                float v = kt[jj4+u][d];
                acc[0] = fmaf(a0[u], v, acc[0]);
                acc[1] = fmaf(a1[u], v, acc[1]);
                acc[2] = fmaf(a2[u], v, acc[2]);
                acc[3] = fmaf(a3[u], v, acc[3]);
            }
        }
        __syncthreads();
    }
    #pragma unroll
    for (int i = 0; i < 4; ++i)
        attn[(size_t)(b*576 + q0 + rb + i)*768 + qoff + d] = acc[i] / ssum[rb+i];
}

// ---------------- gate: scores -> argmax -> expert lists ----------------
__global__ __launch_bounds__(256)
void gate_kernel(const float* __restrict__ h2, const float* __restrict__ gw,
                 const float* __restrict__ gb, float* __restrict__ wgt,
                 int* __restrict__ lists, int* __restrict__ counts)
{
    int tokid = blockIdx.x;
    int t = threadIdx.x;
    const float* hr = h2 + (size_t)tokid*768;
    float p0=0.f,p1=0.f,p2=0.f,p3=0.f;
    for (int k = t; k < 768; k += 256) {
        float hv = hr[k];
        p0 = fmaf(hv, gw[k],        p0);
        p1 = fmaf(hv, gw[768 + k],  p1);
        p2 = fmaf(hv, gw[1536 + k], p2);
        p3 = fmaf(hv, gw[2304 + k], p3);
    }
    for (int off = 32; off > 0; off >>= 1) {
        p0 += __shfl_down(p0, off);
        p1 += __shfl_down(p1, off);
        p2 += __shfl_down(p2, off);
        p3 += __shfl_down(p3, off);
    }
    __shared__ float red[4][4];
    int wv = t >> 6, ln = t & 63;
    if (ln == 0) { red[wv][0]=p0; red[wv][1]=p1; red[wv][2]=p2; red[wv][3]=p3; }
    __syncthreads();
    if (t == 0) {
        float s[4];
        #pragma unroll
        for (int e = 0; e < 4; ++e)
            s[e] = red[0][e]+red[1][e]+red[2][e]+red[3][e] + gb[e];
        int best = 0; float bv = s[0];
        #pragma unroll
        for (int e = 1; e < 4; ++e) if (s[e] > bv) { bv = s[e]; best = e; }  // first-max tie-break
        wgt[tokid] = bv;
        int pos = atomicAdd(&counts[best], 1);
        lists[best*TOK + pos] = tokid;
    }
}

__global__ void zero_counts(int* counts) { if (threadIdx.x < 4) counts[threadIdx.x] = 0; }

// ---------------- final b (h w) c -> b c h w ----------------
__global__ __launch_bounds__(256)
void out_transpose(const float* __restrict__ tok, float* __restrict__ out)
{
    int idx = blockIdx.x*256 + threadIdx.x;   // ((b*768+d)*24+hp)*24+wp
    int wp = idx % 24;
    int hp = (idx / 24) % 24;
    int d  = (idx / 576) % 768;
    int b  = idx / (576*768);
    out[idx] = tok[(size_t)(b*576 + hp*24 + wp)*768 + d];
}

extern "C" void kernel_launch(void* const* d_in, const int* in_sizes, int n_in,
                              void* d_out, int out_size, void* d_ws, size_t ws_size,
                              hipStream_t stream)
{
    const float* x       = (const float*)d_in[0];
    const float* patch_w = (const float*)d_in[1];
    const float* patch_b = (const float*)d_in[2];
    const float* pos     = (const float*)d_in[3];
    const float* ln1_g   = (const float*)d_in[4];
    const float* ln1_b   = (const float*)d_in[5];
    const float* qkv_w   = (const float*)d_in[6];
    const float* qkv_b   = (const float*)d_in[7];
    const float* out_w   = (const float*)d_in[8];
    const float* out_b   = (const float*)d_in[9];
    const float* ln2_g   = (const float*)d_in[10];
    const float* ln2_b   = (const float*)d_in[11];
    const float* gate_w  = (const float*)d_in[12];
    const float* gate_b  = (const float*)d_in[13];
    const float* w1      = (const float*)d_in[14];
    const float* b1      = (const float*)d_in[15];
    const float* w2      = (const float*)d_in[16];
    const float* b2      = (const float*)d_in[17];
    float* out = (float*)d_out;

    // workspace layout (floats): tok | h | scratch{qkv,attn} (hid aliases scratch) | wgt | lists | counts
    float* ws    = (float*)d_ws;
    float* tok   = ws;                       // 3,538,944
    float* h     = ws + 3538944;             // 3,538,944
    float* scr   = ws + 7077888;             // 14,155,776 (qkv 10,616,832 + attn 3,538,944)
    float* qkv   = scr;
    float* attn  = scr + 10616832;
    float* hid   = scr;                      // aliases qkv+attn (dead by FFN time)
    float* wgt   = ws + 21233664;            // 4608
    int*   lists = (int*)(ws + 21238272);    // 4*4608
    int*   counts= (int*)(ws + 21256704);    // 4

    patch_embed_kernel<<<4608, 256, 0, stream>>>(x, patch_w, patch_b, pos, tok);

    for (int l = 0; l < 12; ++l) {
        ln_kernel<<<4608, 256, 0, stream>>>(tok, h, ln1_g + l*768, ln1_b + l*768);
        gemm_nt<<<dim3(36,72,1), 256, 0, stream>>>(h, qkv_w + (size_t)l*2304*768, qkv_b + l*2304,
                                                   qkv, 4608, 2304, 768, 768, 2304, 0,
                                                   nullptr, nullptr, nullptr);
        attn_kernel<<<dim3(36,12,8), 256, 0, stream>>>(qkv, attn);
        gemm_nt<<<dim3(12,72,1), 256, 0, stream>>>(attn, out_w + (size_t)l*768*768, out_b + l*768,
                                                   tok, 4608, 768, 768, 768, 768, 1,
                                                   nullptr, nullptr, nullptr);
        ln_kernel<<<4608, 256, 0, stream>>>(tok, h, ln2_g + l*768, ln2_b + l*768);
        zero_counts<<<1, 64, 0, stream>>>(counts);
        gate_kernel<<<4608, 256, 0, stream>>>(h, gate_w + l*3072, gate_b + l*4, wgt, lists, counts);
        gemm_nt<<<dim3(48,72,4), 256, 0, stream>>>(h, w1 + (size_t)l*4*3072*768, b1 + (size_t)l*4*3072,
                                                   hid, 4608, 3072, 768, 768, 3072, 2,
                                                   lists, counts, nullptr);
        gemm_nt<<<dim3(12,72,4), 256, 0, stream>>>(hid, w2 + (size_t)l*4*768*3072, b2 + (size_t)l*4*768,
                                                   tok, 4608, 768, 3072, 3072, 768, 3,
                                                   lists, counts, wgt);
    }
    out_transpose<<<13824, 256, 0, stream>>>(tok, out);
}